// Round 12
// baseline (253.453 us; speedup 1.0000x reference)
//
#include <hip/hip_runtime.h>
#include <hip/hip_fp16.h>

// ---------------------------------------------------------------------------
// GCN 3-layer forward on MI355X.
//   per layer: y = relu( A_hat @ (x @ W) + b )
// Norm folded into transform: H'[r] = (X W)[r] * dinv[r]  (stored fp16), so
//   y[i] = relu( dinv[i] * ( H'[i] + sum_{e: src->i} H'[src] ) + b )
// Activations between layers kept in fp16 (final layer writes fp32 d_out).
//
// CSR build is write-amplification-aware (per-XCD L2s non-coherent; every
// bulk line is written by a single block):  zero -> bin -> bscan -> finalize.
// gemm: MFMA 16x16x32 f16, swapped operands (D=(XW)^T) -> packed 8B stores.
// agg:  XCD-feature-partitioned: H rows are 2 cache lines; blocks on XCDs
//       0-3 (bid%8<4) aggregate features 0-31 (even lines), XCDs 4-7 the
//       odd lines -> per-XCD L2 gather footprint halves (12.8 -> 6.4 MB).
//       Per wave: 2 nodes x 8 slot-groups x 4 lanes x 16B, unroll 2.
// ---------------------------------------------------------------------------

#define THREADS 256
#define BSH     9                  // 512 nodes per bucket
#define BNODES  512
#define BCAP    9216               // mean 8192 edges/bucket + ~11 sigma
#define BPAD    16                 // bucket cursor stride (ints) = 64B line
#define CHUNK   4096               // edges per bin block
// NB = ceil(N/512) must be <= 256 (N=100k -> 196).

#if defined(__has_builtin)
#if __has_builtin(__builtin_amdgcn_fdot2) && __has_builtin(__builtin_amdgcn_perm)
#define USE_DOT2 1
#endif
#endif

typedef __attribute__((ext_vector_type(2))) _Float16 h2v;
typedef __attribute__((ext_vector_type(8))) _Float16 f16x8;
typedef __attribute__((ext_vector_type(4))) float    f32x4;

__global__ __launch_bounds__(THREADS)
void zero_kernel(int* __restrict__ p, int n) {
    int i = blockIdx.x * blockDim.x + threadIdx.x;
    if (i < n) p[i] = 0;
}

// ---- bin: chunk -> per-bucket contiguous runs --------------------------
__global__ __launch_bounds__(THREADS)
void bin_kernel(const int* __restrict__ src, const int* __restrict__ dst,
                int* __restrict__ bcur, int* __restrict__ sbuf, int E) {
    __shared__ int cntb[THREADS];
    __shared__ int lstart[THREADS];
    __shared__ int gbase[THREADS];
    __shared__ int lcur[THREADS];
    __shared__ int tmp[THREADS];
    __shared__ int stagep[CHUNK];
    __shared__ unsigned char stageb[CHUNK];
    int tid = threadIdx.x;
    int e0  = blockIdx.x * CHUNK;
    int cnt = min(CHUNK, E - e0);
    int dreg[16];                       // dst cached in regs (one read)
#pragma unroll
    for (int j = 0; j < 16; ++j) {
        int i = tid + j * THREADS;
        dreg[j] = (i < cnt) ? dst[e0 + i] : -1;
    }
    cntb[tid] = 0;
    __syncthreads();
#pragma unroll
    for (int j = 0; j < 16; ++j)
        if (dreg[j] >= 0) atomicAdd(&cntb[dreg[j] >> BSH], 1);
    __syncthreads();
    int v = cntb[tid];
    tmp[tid] = v;
    __syncthreads();
    for (int off = 1; off < THREADS; off <<= 1) {
        int t = (tid >= off) ? tmp[tid - off] : 0;
        __syncthreads();
        tmp[tid] += t;
        __syncthreads();
    }
    lstart[tid] = tmp[tid] - v;
    lcur[tid]   = 0;
    if (v > 0) gbase[tid] = atomicAdd(&bcur[tid * BPAD], v);  // one per bucket
    __syncthreads();
#pragma unroll
    for (int j = 0; j < 16; ++j) {      // stage ordered by bucket
        int i = tid + j * THREADS;
        if (i < cnt) {
            int s = src[e0 + i];
            int d = dreg[j];
            int b = d >> BSH;
            int pos = atomicAdd(&lcur[b], 1);
            int idx = lstart[b] + pos;
            stagep[idx] = (s << BSH) | (d & (BNODES - 1));
            stageb[idx] = (unsigned char)b;
        }
    }
    __syncthreads();
    for (int i = tid; i < cnt; i += THREADS) {   // contiguous run copy-out
        int b = stageb[i];
        sbuf[(size_t)b * BCAP + gbase[b] + (i - lstart[b])] = stagep[i];
    }
}

// ---- exclusive scan of bucket counts -> bbase; rowptr[N] = E -----------
__global__ __launch_bounds__(THREADS)
void bscan_kernel(const int* __restrict__ bcur, int* __restrict__ bbase,
                  int NB, int* __restrict__ rowptr, int N, int E) {
    __shared__ int tmp[THREADS];
    int tid = threadIdx.x;
    int c = (tid < NB) ? min(bcur[tid * BPAD], BCAP) : 0;
    tmp[tid] = c;
    __syncthreads();
    for (int off = 1; off < THREADS; off <<= 1) {
        int t = (tid >= off) ? tmp[tid - off] : 0;
        __syncthreads();
        tmp[tid] += t;
        __syncthreads();
    }
    if (tid < NB) bbase[tid] = tmp[tid] - c;
    if (tid == 0) rowptr[N] = E;
}

// ---- finalize: per-bucket CSR (single block -> single CU writes) -------
__global__ __launch_bounds__(THREADS)
void finalize_kernel(const int* __restrict__ sbuf, const int* __restrict__ bcur,
                     const int* __restrict__ bbase, int* __restrict__ rowptr,
                     float* __restrict__ dinv, int* __restrict__ csrc, int N) {
    __shared__ int lcnt[BNODES];
    __shared__ int lexcl[BNODES];
    __shared__ int lcur[BNODES];
    __shared__ int tmp[THREADS];
    int b   = blockIdx.x;
    int tid = threadIdx.x;
    int cnt = min(bcur[b * BPAD], BCAP);
    int gb  = bbase[b];
    const int* sb = sbuf + (size_t)b * BCAP;
    for (int i = tid; i < BNODES; i += THREADS) { lcnt[i] = 0; lcur[i] = 0; }
    __syncthreads();
    for (int e = tid; e < cnt; e += THREADS)
        atomicAdd(&lcnt[sb[e] & (BNODES - 1)], 1);
    __syncthreads();
    int a0 = lcnt[2 * tid], a1 = lcnt[2 * tid + 1];
    int s  = a0 + a1;
    tmp[tid] = s;
    __syncthreads();
    for (int off = 1; off < THREADS; off <<= 1) {
        int t = (tid >= off) ? tmp[tid - off] : 0;
        __syncthreads();
        tmp[tid] += t;
        __syncthreads();
    }
    int ex = tmp[tid] - s;
    lexcl[2 * tid]     = ex;
    lexcl[2 * tid + 1] = ex + a0;
    int node = (b << BSH) + 2 * tid;
    if (node < N) {
        rowptr[node] = gb + ex;
        dinv[node]   = rsqrtf((float)(a0 + 1));   // +1 self-loop
    }
    if (node + 1 < N) {
        rowptr[node + 1] = gb + ex + a0;
        dinv[node + 1]   = rsqrtf((float)(a1 + 1));
    }
    __syncthreads();
    for (int e = tid; e < cnt; e += THREADS) {
        int vv  = sb[e];
        int d   = vv & (BNODES - 1);
        int pos = atomicAdd(&lcur[d], 1);
        csrc[gb + lexcl[d] + pos] = vv >> BSH;
    }
}

// ---- transform: H[r,:] = fp16( (X[r,:] @ W) * dinv[r] ), MFMA ----------
// Swapped-operand form: D = (W^T frag)·(X^T frag) = (X·W)^T tile.
// IT = float (layer 0) or __half (layers 1,2).
template <typename IT>
__global__ __launch_bounds__(THREADS)
void gemm64_kernel(const IT* __restrict__ X, __half* __restrict__ H,
                   const float* __restrict__ W, const float* __restrict__ dinv,
                   int n) {
    int lane = threadIdx.x & 63;
    int qk   = lane >> 4;        // 0..3 (k-quarter / feature-quarter)
    int l16  = lane & 15;
    // W fragments: tile t (out-features 16t..16t+15), k-slice h (k=32h..+31)
    f16x8 bf[4][2];
#pragma unroll
    for (int t = 0; t < 4; ++t)
#pragma unroll
        for (int h = 0; h < 2; ++h) {
            const float* wp = W + (size_t)(32 * h + qk * 8) * 64 + 16 * t + l16;
#pragma unroll
            for (int j = 0; j < 8; ++j)
                bf[t][h][j] = (_Float16)wp[j * 64];
        }
    int wave  = (blockIdx.x * blockDim.x + threadIdx.x) >> 6;
    int nw    = (gridDim.x * blockDim.x) >> 6;
    int ntile = (n + 15) >> 4;
    for (int tile = wave; tile < ntile; tile += nw) {
        int rbase = tile << 4;
        int arow  = rbase + l16;
        if (arow >= n) arow = n - 1;            // tail guard (loads only)
        f16x8 A0, A1;
        if constexpr (sizeof(IT) == 4) {
            const float4* xp = (const float4*)((const float*)X + (size_t)arow * 64 + qk * 8);
            float4 a0 = xp[0], a1 = xp[1];      // k-slice 0
            float4 a2 = xp[8], a3 = xp[9];      // k-slice 1 (+32 floats)
            A0[0] = (_Float16)a0.x; A0[1] = (_Float16)a0.y;
            A0[2] = (_Float16)a0.z; A0[3] = (_Float16)a0.w;
            A0[4] = (_Float16)a1.x; A0[5] = (_Float16)a1.y;
            A0[6] = (_Float16)a1.z; A0[7] = (_Float16)a1.w;
            A1[0] = (_Float16)a2.x; A1[1] = (_Float16)a2.y;
            A1[2] = (_Float16)a2.z; A1[3] = (_Float16)a2.w;
            A1[4] = (_Float16)a3.x; A1[5] = (_Float16)a3.y;
            A1[6] = (_Float16)a3.z; A1[7] = (_Float16)a3.w;
        } else {
            const int4* xp = (const int4*)((const __half*)X + (size_t)arow * 64 + qk * 8);
            A0 = __builtin_bit_cast(f16x8, xp[0]);   // halves k 0..7 of slice
            A1 = __builtin_bit_cast(f16x8, xp[4]);   // +32 halves
        }
        f32x4 acc[4];
#pragma unroll
        for (int t = 0; t < 4; ++t) {
            acc[t] = (f32x4){0.f, 0.f, 0.f, 0.f};
            // swapped operands: W^T frag as A, X^T frag as B
            acc[t] = __builtin_amdgcn_mfma_f32_16x16x32_f16(bf[t][0], A0, acc[t], 0, 0, 0);
            acc[t] = __builtin_amdgcn_mfma_f32_16x16x32_f16(bf[t][1], A1, acc[t], 0, 0, 0);
        }
        int row = rbase + l16;
        if (row < n) {
            float dv = dinv[row];
            __half* hp = H + (size_t)row * 64 + qk * 4;   // 8B-aligned
#pragma unroll
            for (int t = 0; t < 4; ++t) {
                __half2 p0 = __floats2half2_rn(acc[t][0] * dv, acc[t][1] * dv);
                __half2 p1 = __floats2half2_rn(acc[t][2] * dv, acc[t][3] * dv);
                int2 pv;
                pv.x = *(const int*)&p0;
                pv.y = *(const int*)&p1;
                *(int2*)(hp + 16 * t) = pv;   // features 16t+qk*4 .. +3
            }
        }
    }
}

// ---- aggregate (XCD-feature-partitioned) -------------------------------
// y[i, f*32 .. f*32+31] = relu(dinv[i]*(H[i,half]+sum H[src,half]) + b)
// f = (blockIdx>>2)&1: with XCD = bid%8, XCDs 0-3 own even H-lines (f=0),
// XCDs 4-7 odd lines (f=1) -> per-XCD gather footprint halves.
// Per wave: 2 nodes (lane>>5); per node 8 slot-groups x 4 lanes x 16B.
__device__ __forceinline__ void pairdot(const int4& hA, const int4& hB,
                                        bool vA, bool vB, float* accf) {
#ifdef USE_DOT2
    unsigned mb = (vA ? 0x3C00u : 0u) | (vB ? 0x3C000000u : 0u);
    h2v m2 = __builtin_bit_cast(h2v, mb);
    const unsigned* pa = (const unsigned*)&hA;
    const unsigned* pb = (const unsigned*)&hB;
#pragma unroll
    for (int j = 0; j < 4; ++j) {
        unsigned p0 = __builtin_amdgcn_perm(pb[j], pa[j], 0x05040100);
        unsigned p1 = __builtin_amdgcn_perm(pb[j], pa[j], 0x07060302);
        accf[2 * j]     = __builtin_amdgcn_fdot2(
            __builtin_bit_cast(h2v, p0), m2, accf[2 * j], false);
        accf[2 * j + 1] = __builtin_amdgcn_fdot2(
            __builtin_bit_cast(h2v, p1), m2, accf[2 * j + 1], false);
    }
#else
    float mA = vA ? 1.f : 0.f, mB = vB ? 1.f : 0.f;
    const __half2* ha = (const __half2*)&hA;
    const __half2* hb = (const __half2*)&hB;
#pragma unroll
    for (int j = 0; j < 4; ++j) {
        float2 fa = __half22float2(ha[j]);
        float2 fb = __half22float2(hb[j]);
        accf[2 * j]     = fmaf(fa.x, mA, accf[2 * j]);
        accf[2 * j]     = fmaf(fb.x, mB, accf[2 * j]);
        accf[2 * j + 1] = fmaf(fa.y, mA, accf[2 * j + 1]);
        accf[2 * j + 1] = fmaf(fb.y, mB, accf[2 * j + 1]);
    }
#endif
}

// OT = __half (layers 0,1) or float (layer 2 -> d_out)
template <typename OT>
__global__ __launch_bounds__(THREADS)
void agg_kernel(const __half* __restrict__ H, OT* __restrict__ Y,
                const int* __restrict__ rowptr, const int* __restrict__ csrc,
                const float* __restrict__ dinv, const float* __restrict__ bias,
                int n) {
    int bid  = blockIdx.x;
    int f    = (bid >> 2) & 1;              // XCDs 0-3 -> f=0; 4-7 -> f=1
    int lb   = (bid >> 3) * 4 + (bid & 3);  // logical block within its half
    int nlb  = (int)gridDim.x >> 1;
    int lane = threadIdx.x & 63;
    int half = lane >> 5;          // which node of the pair
    int hl   = lane & 31;
    int grp  = hl >> 2;            // 0..7 edge-slot group
    int sub  = lane & 3;           // 16B chunk within the 64B half-row
    int fl   = f * 32 + sub * 8;   // first feature of this lane
    int hoff = f * 4 + sub;        // int4 offset within a 128B H row
    const int4* H4 = (const int4*)H;
    int wave = lb * (THREADS >> 6) + ((int)threadIdx.x >> 6);
    int nw   = nlb * (THREADS >> 6);
    int np   = (n + 1) >> 1;       // node pairs
    float4 bv0 = *(const float4*)(bias + fl);
    float4 bv1 = *(const float4*)(bias + fl + 4);
    int wp = wave;
    if (wp >= np) return;
    int node = min(2 * wp + half, n - 1);
    int k0 = rowptr[node], k1 = rowptr[node + 1];
    while (true) {
        // prefetch next pair's rowptr (independent of everything below)
        int wpn = wp + nw;
        int noden = 0, k0n = 0, k1n = 0;
        bool more = wpn < np;
        if (more) {
            noden = min(2 * wpn + half, n - 1);
            k0n = rowptr[noden];
            k1n = rowptr[noden + 1];
        }
        float accf[8] = {0.f, 0.f, 0.f, 0.f, 0.f, 0.f, 0.f, 0.f};
        if (grp == 0) {  // self-loop half-row (4 lanes per node)
            int4 hv = H4[(size_t)node * 8 + hoff];
            const __half2* hh = (const __half2*)&hv;
#pragma unroll
            for (int j = 0; j < 4; ++j) {
                float2 fe = __half22float2(hh[j]);
                accf[2 * j]     += fe.x;
                accf[2 * j + 1] += fe.y;
            }
        }
        for (int basek = k0; basek < k1; basek += 16) {
            int  kk0 = basek + grp;          // grp 0..7; unroll 2 -> 16 slots
            int  kk1 = kk0 + 8;
            bool v0 = kk0 < k1, v1 = kk1 < k1;
            int  s0 = v0 ? csrc[kk0] : 0;    // masked -> row 0 (L1-hot)
            int  s1 = v1 ? csrc[kk1] : 0;
            int4 h0 = H4[(size_t)s0 * 8 + hoff];   // 64B/slot: one line
            int4 h1 = H4[(size_t)s1 * 8 + hoff];
            pairdot(h0, h1, v0, v1, accf);
        }
        // reduce partials across the 8 groups of this half (stride 4, 8, 16)
#pragma unroll
        for (int j = 0; j < 8; ++j) {
            float a = accf[j];
            a += __shfl_xor(a, 4);
            a += __shfl_xor(a, 8);
            a += __shfl_xor(a, 16);
            accf[j] = a;
        }
        if (grp == 0 && 2 * wp + half < n) {
            float di = dinv[node];
            float o[8];
            o[0] = fmaxf(fmaf(accf[0], di, bv0.x), 0.f);
            o[1] = fmaxf(fmaf(accf[1], di, bv0.y), 0.f);
            o[2] = fmaxf(fmaf(accf[2], di, bv0.z), 0.f);
            o[3] = fmaxf(fmaf(accf[3], di, bv0.w), 0.f);
            o[4] = fmaxf(fmaf(accf[4], di, bv1.x), 0.f);
            o[5] = fmaxf(fmaf(accf[5], di, bv1.y), 0.f);
            o[6] = fmaxf(fmaf(accf[6], di, bv1.z), 0.f);
            o[7] = fmaxf(fmaf(accf[7], di, bv1.w), 0.f);
            if constexpr (sizeof(OT) == 2) {
                __half2 hh[4];
#pragma unroll
                for (int j = 0; j < 4; ++j)
                    hh[j] = __floats2half2_rn(o[2 * j], o[2 * j + 1]);
                *(int4*)((__half*)Y + (size_t)node * 64 + fl) =
                    *(const int4*)hh;     // 4 lanes x 16B = 64B half-row
            } else {
                float4 o0 = make_float4(o[0], o[1], o[2], o[3]);
                float4 o1 = make_float4(o[4], o[5], o[6], o[7]);
                *(float4*)((float*)Y + (size_t)node * 64 + fl)     = o0;
                *(float4*)((float*)Y + (size_t)node * 64 + fl + 4) = o1;
            }
        }
        if (!more) break;
        wp = wpn; node = noden; k0 = k0n; k1 = k1n;
    }
}

extern "C" void kernel_launch(void* const* d_in, const int* in_sizes, int n_in,
                              void* d_out, int out_size, void* d_ws, size_t ws_size,
                              hipStream_t stream) {
    const float* x  = (const float*)d_in[0];
    const int*   ei = (const int*)d_in[1];
    const float* W0 = (const float*)d_in[2];
    const float* b0 = (const float*)d_in[3];
    const float* W1 = (const float*)d_in[4];
    const float* b1 = (const float*)d_in[5];
    const float* W2 = (const float*)d_in[6];
    const float* b2 = (const float*)d_in[7];

    const int N = in_sizes[0] / 64;
    const int E = in_sizes[1] / 2;
    const int* src = ei;       // edge_index[0]
    const int* dst = ei + E;   // edge_index[1]
    const int NB = (N + BNODES - 1) >> BSH;   // 196 for N=100k (<=256)

    // ---- workspace layout (256B-aligned slices) ----
    char*  ws  = (char*)d_ws;
    size_t off = 0;
    auto alloc = [&](size_t bytes) -> void* {
        void* p = ws + off;
        off += (bytes + 255) & ~(size_t)255;
        return p;
    };
    int*    rowptr = (int*)   alloc((size_t)(N + 1) * 4);
    float*  dinv   = (float*) alloc((size_t)N * 4);
    int*    csrc   = (int*)   alloc((size_t)E * 4);
    int*    bcur   = (int*)   alloc((size_t)NB * BPAD * 4);
    int*    bbase  = (int*)   alloc((size_t)NB * 4);
    int*    sbuf   = (int*)   alloc((size_t)NB * BCAP * 4);
    __half* hbuf   = (__half*)alloc((size_t)N * 64 * 2);
    __half* act16  = (__half*)alloc((size_t)N * 64 * 2);
    float*  outb   = (float*)d_out;

    const int ngrid = 2048;   // agg: multiple of 8 (XCD partition) = 8/CU
    const int ggrid = 1024;   // gemm (MFMA)
    const int bgrid = (E + CHUNK - 1) / CHUNK;
    const int zn    = NB * BPAD;

    zero_kernel    <<<(zn + THREADS - 1) / THREADS, THREADS, 0, stream>>>(bcur, zn);
    bin_kernel     <<<bgrid, THREADS, 0, stream>>>(src, dst, bcur, sbuf, E);
    bscan_kernel   <<<1,     THREADS, 0, stream>>>(bcur, bbase, NB, rowptr, N, E);
    finalize_kernel<<<NB,    THREADS, 0, stream>>>(sbuf, bcur, bbase, rowptr,
                                                   dinv, csrc, N);

    // layer 0: x(f32) -> hbuf -> act16 (fp16)
    gemm64_kernel<float> <<<ggrid, THREADS, 0, stream>>>(x, hbuf, W0, dinv, N);
    agg_kernel<__half>   <<<ngrid, THREADS, 0, stream>>>(hbuf, act16, rowptr, csrc, dinv, b0, N);
    // layer 1: act16 -> hbuf -> act16
    gemm64_kernel<__half><<<ggrid, THREADS, 0, stream>>>(act16, hbuf, W1, dinv, N);
    agg_kernel<__half>   <<<ngrid, THREADS, 0, stream>>>(hbuf, act16, rowptr, csrc, dinv, b1, N);
    // layer 2: act16 -> hbuf -> d_out (fp32)
    gemm64_kernel<__half><<<ggrid, THREADS, 0, stream>>>(act16, hbuf, W2, dinv, N);
    agg_kernel<float>    <<<ngrid, THREADS, 0, stream>>>(hbuf, outb, rowptr, csrc, dinv, b2, N);
}

// Round 13
// 185.228 us; speedup vs baseline: 1.3683x; 1.3683x over previous
//
#include <hip/hip_runtime.h>
#include <hip/hip_fp16.h>

// ---------------------------------------------------------------------------
// GCN 3-layer forward on MI355X.  (Revert to round-10 structure = measured
// best, 185.7us. r9 csrc-prefetch, r11 operand-swap, r12 XCD-partition all
// measured neutral-or-worse.)
//   per layer: y = relu( A_hat @ (x @ W) + b )
// Norm folded into transform: H'[r] = (X W)[r] * dinv[r]  (stored fp16), so
//   y[i] = relu( dinv[i] * ( H'[i] + sum_{e: src->i} H'[src] ) + b )
// Activations between layers kept in fp16 (final layer writes fp32 d_out).
//
// CSR build is write-amplification-aware (per-XCD L2s non-coherent; every
// bulk line is written by a single block):  zero -> bin -> bscan -> finalize.
// gemm: MFMA 16x16x32 f16, one wave per 16-row tile; W frags in VGPRs.
// agg:  2 nodes/wave (4 groups x 8 lanes x 16B gathers, 16 slots/node in
//       flight), rowptr prefetched one node-pair ahead,
//       masked slots gather the L1-hot row 0, v_perm+v_dot2_f32_f16.
// ---------------------------------------------------------------------------

#define THREADS 256
#define BSH     9                  // 512 nodes per bucket
#define BNODES  512
#define BCAP    9216               // mean 8192 edges/bucket + ~11 sigma
#define BPAD    16                 // bucket cursor stride (ints) = 64B line
#define CHUNK   4096               // edges per bin block
// NB = ceil(N/512) must be <= 256 (N=100k -> 196).

#if defined(__has_builtin)
#if __has_builtin(__builtin_amdgcn_fdot2) && __has_builtin(__builtin_amdgcn_perm)
#define USE_DOT2 1
#endif
#endif

typedef __attribute__((ext_vector_type(2))) _Float16 h2v;
typedef __attribute__((ext_vector_type(8))) _Float16 f16x8;
typedef __attribute__((ext_vector_type(4))) float    f32x4;

__global__ __launch_bounds__(THREADS)
void zero_kernel(int* __restrict__ p, int n) {
    int i = blockIdx.x * blockDim.x + threadIdx.x;
    if (i < n) p[i] = 0;
}

// ---- bin: chunk -> per-bucket contiguous runs --------------------------
__global__ __launch_bounds__(THREADS)
void bin_kernel(const int* __restrict__ src, const int* __restrict__ dst,
                int* __restrict__ bcur, int* __restrict__ sbuf, int E) {
    __shared__ int cntb[THREADS];
    __shared__ int lstart[THREADS];
    __shared__ int gbase[THREADS];
    __shared__ int lcur[THREADS];
    __shared__ int tmp[THREADS];
    __shared__ int stagep[CHUNK];
    __shared__ unsigned char stageb[CHUNK];
    int tid = threadIdx.x;
    int e0  = blockIdx.x * CHUNK;
    int cnt = min(CHUNK, E - e0);
    int dreg[16];                       // dst cached in regs (one read)
#pragma unroll
    for (int j = 0; j < 16; ++j) {
        int i = tid + j * THREADS;
        dreg[j] = (i < cnt) ? dst[e0 + i] : -1;
    }
    cntb[tid] = 0;
    __syncthreads();
#pragma unroll
    for (int j = 0; j < 16; ++j)
        if (dreg[j] >= 0) atomicAdd(&cntb[dreg[j] >> BSH], 1);
    __syncthreads();
    int v = cntb[tid];
    tmp[tid] = v;
    __syncthreads();
    for (int off = 1; off < THREADS; off <<= 1) {
        int t = (tid >= off) ? tmp[tid - off] : 0;
        __syncthreads();
        tmp[tid] += t;
        __syncthreads();
    }
    lstart[tid] = tmp[tid] - v;
    lcur[tid]   = 0;
    if (v > 0) gbase[tid] = atomicAdd(&bcur[tid * BPAD], v);  // one per bucket
    __syncthreads();
#pragma unroll
    for (int j = 0; j < 16; ++j) {      // stage ordered by bucket
        int i = tid + j * THREADS;
        if (i < cnt) {
            int s = src[e0 + i];
            int d = dreg[j];
            int b = d >> BSH;
            int pos = atomicAdd(&lcur[b], 1);
            int idx = lstart[b] + pos;
            stagep[idx] = (s << BSH) | (d & (BNODES - 1));
            stageb[idx] = (unsigned char)b;
        }
    }
    __syncthreads();
    for (int i = tid; i < cnt; i += THREADS) {   // contiguous run copy-out
        int b = stageb[i];
        sbuf[(size_t)b * BCAP + gbase[b] + (i - lstart[b])] = stagep[i];
    }
}

// ---- exclusive scan of bucket counts -> bbase; rowptr[N] = E -----------
__global__ __launch_bounds__(THREADS)
void bscan_kernel(const int* __restrict__ bcur, int* __restrict__ bbase,
                  int NB, int* __restrict__ rowptr, int N, int E) {
    __shared__ int tmp[THREADS];
    int tid = threadIdx.x;
    int c = (tid < NB) ? min(bcur[tid * BPAD], BCAP) : 0;
    tmp[tid] = c;
    __syncthreads();
    for (int off = 1; off < THREADS; off <<= 1) {
        int t = (tid >= off) ? tmp[tid - off] : 0;
        __syncthreads();
        tmp[tid] += t;
        __syncthreads();
    }
    if (tid < NB) bbase[tid] = tmp[tid] - c;
    if (tid == 0) rowptr[N] = E;
}

// ---- finalize: per-bucket CSR (single block -> single CU writes) -------
__global__ __launch_bounds__(THREADS)
void finalize_kernel(const int* __restrict__ sbuf, const int* __restrict__ bcur,
                     const int* __restrict__ bbase, int* __restrict__ rowptr,
                     float* __restrict__ dinv, int* __restrict__ csrc, int N) {
    __shared__ int lcnt[BNODES];
    __shared__ int lexcl[BNODES];
    __shared__ int lcur[BNODES];
    __shared__ int tmp[THREADS];
    int b   = blockIdx.x;
    int tid = threadIdx.x;
    int cnt = min(bcur[b * BPAD], BCAP);
    int gb  = bbase[b];
    const int* sb = sbuf + (size_t)b * BCAP;
    for (int i = tid; i < BNODES; i += THREADS) { lcnt[i] = 0; lcur[i] = 0; }
    __syncthreads();
    for (int e = tid; e < cnt; e += THREADS)
        atomicAdd(&lcnt[sb[e] & (BNODES - 1)], 1);
    __syncthreads();
    int a0 = lcnt[2 * tid], a1 = lcnt[2 * tid + 1];
    int s  = a0 + a1;
    tmp[tid] = s;
    __syncthreads();
    for (int off = 1; off < THREADS; off <<= 1) {
        int t = (tid >= off) ? tmp[tid - off] : 0;
        __syncthreads();
        tmp[tid] += t;
        __syncthreads();
    }
    int ex = tmp[tid] - s;
    lexcl[2 * tid]     = ex;
    lexcl[2 * tid + 1] = ex + a0;
    int node = (b << BSH) + 2 * tid;
    if (node < N) {
        rowptr[node] = gb + ex;
        dinv[node]   = rsqrtf((float)(a0 + 1));   // +1 self-loop
    }
    if (node + 1 < N) {
        rowptr[node + 1] = gb + ex + a0;
        dinv[node + 1]   = rsqrtf((float)(a1 + 1));
    }
    __syncthreads();
    for (int e = tid; e < cnt; e += THREADS) {
        int vv  = sb[e];
        int d   = vv & (BNODES - 1);
        int pos = atomicAdd(&lcur[d], 1);
        csrc[gb + lexcl[d] + pos] = vv >> BSH;
    }
}

// ---- transform: H[r,:] = fp16( (X[r,:] @ W) * dinv[r] ), MFMA ----------
// IT = float (layer 0) or __half (layers 1,2).
template <typename IT>
__global__ __launch_bounds__(THREADS)
void gemm64_kernel(const IT* __restrict__ X, __half* __restrict__ H,
                   const float* __restrict__ W, const float* __restrict__ dinv,
                   int n) {
    int lane = threadIdx.x & 63;
    int qk   = lane >> 4;        // 0..3 (k-quarter / row-quarter)
    int l16  = lane & 15;
    // B fragments: col tile t (cols 16t..16t+15), k-slice h (k = 32h..32h+31)
    f16x8 bf[4][2];
#pragma unroll
    for (int t = 0; t < 4; ++t)
#pragma unroll
        for (int h = 0; h < 2; ++h) {
            const float* wp = W + (size_t)(32 * h + qk * 8) * 64 + 16 * t + l16;
#pragma unroll
            for (int j = 0; j < 8; ++j)
                bf[t][h][j] = (_Float16)wp[j * 64];
        }
    int wave  = (blockIdx.x * blockDim.x + threadIdx.x) >> 6;
    int nw    = (gridDim.x * blockDim.x) >> 6;
    int ntile = (n + 15) >> 4;
    for (int tile = wave; tile < ntile; tile += nw) {
        int rbase = tile << 4;
        int arow  = rbase + l16;
        if (arow >= n) arow = n - 1;            // tail guard (loads only)
        f16x8 A0, A1;
        if constexpr (sizeof(IT) == 4) {
            const float4* xp = (const float4*)((const float*)X + (size_t)arow * 64 + qk * 8);
            float4 a0 = xp[0], a1 = xp[1];      // k-slice 0
            float4 a2 = xp[8], a3 = xp[9];      // k-slice 1 (+32 floats)
            A0[0] = (_Float16)a0.x; A0[1] = (_Float16)a0.y;
            A0[2] = (_Float16)a0.z; A0[3] = (_Float16)a0.w;
            A0[4] = (_Float16)a1.x; A0[5] = (_Float16)a1.y;
            A0[6] = (_Float16)a1.z; A0[7] = (_Float16)a1.w;
            A1[0] = (_Float16)a2.x; A1[1] = (_Float16)a2.y;
            A1[2] = (_Float16)a2.z; A1[3] = (_Float16)a2.w;
            A1[4] = (_Float16)a3.x; A1[5] = (_Float16)a3.y;
            A1[6] = (_Float16)a3.z; A1[7] = (_Float16)a3.w;
        } else {
            const int4* xp = (const int4*)((const __half*)X + (size_t)arow * 64 + qk * 8);
            A0 = __builtin_bit_cast(f16x8, xp[0]);   // halves k 0..7 of slice
            A1 = __builtin_bit_cast(f16x8, xp[4]);   // +32 halves
        }
        f32x4 acc[4];
#pragma unroll
        for (int t = 0; t < 4; ++t) {
            acc[t] = (f32x4){0.f, 0.f, 0.f, 0.f};
            acc[t] = __builtin_amdgcn_mfma_f32_16x16x32_f16(A0, bf[t][0], acc[t], 0, 0, 0);
            acc[t] = __builtin_amdgcn_mfma_f32_16x16x32_f16(A1, bf[t][1], acc[t], 0, 0, 0);
        }
#pragma unroll
        for (int r = 0; r < 4; ++r) {
            int row = rbase + qk * 4 + r;
            if (row < n) {
                float dv = dinv[row];
                __half* hp = H + (size_t)row * 64 + l16;
#pragma unroll
                for (int t = 0; t < 4; ++t)
                    hp[16 * t] = __float2half(acc[t][r] * dv);
            }
        }
    }
}

// ---- aggregate: y[i,:] = relu(dinv[i]*(H[i,:]+sum H[src,:]) + b) -------
// 2 nodes/wave; per node 4 groups x 8 lanes x 16B, 16 slots in flight.
// rowptr for the next node-pair prefetched at loop top.
__device__ __forceinline__ void pairdot(const int4& hA, const int4& hB,
                                        bool vA, bool vB, float* accf) {
#ifdef USE_DOT2
    unsigned mb = (vA ? 0x3C00u : 0u) | (vB ? 0x3C000000u : 0u);
    h2v m2 = __builtin_bit_cast(h2v, mb);
    const unsigned* pa = (const unsigned*)&hA;
    const unsigned* pb = (const unsigned*)&hB;
#pragma unroll
    for (int j = 0; j < 4; ++j) {
        unsigned p0 = __builtin_amdgcn_perm(pb[j], pa[j], 0x05040100);
        unsigned p1 = __builtin_amdgcn_perm(pb[j], pa[j], 0x07060302);
        accf[2 * j]     = __builtin_amdgcn_fdot2(
            __builtin_bit_cast(h2v, p0), m2, accf[2 * j], false);
        accf[2 * j + 1] = __builtin_amdgcn_fdot2(
            __builtin_bit_cast(h2v, p1), m2, accf[2 * j + 1], false);
    }
#else
    float mA = vA ? 1.f : 0.f, mB = vB ? 1.f : 0.f;
    const __half2* ha = (const __half2*)&hA;
    const __half2* hb = (const __half2*)&hB;
#pragma unroll
    for (int j = 0; j < 4; ++j) {
        float2 fa = __half22float2(ha[j]);
        float2 fb = __half22float2(hb[j]);
        accf[2 * j]     = fmaf(fa.x, mA, accf[2 * j]);
        accf[2 * j]     = fmaf(fb.x, mB, accf[2 * j]);
        accf[2 * j + 1] = fmaf(fa.y, mA, accf[2 * j + 1]);
        accf[2 * j + 1] = fmaf(fb.y, mB, accf[2 * j + 1]);
    }
#endif
}

// OT = __half (layers 0,1) or float (layer 2 -> d_out)
template <typename OT>
__global__ __launch_bounds__(THREADS)
void agg_kernel(const __half* __restrict__ H, OT* __restrict__ Y,
                const int* __restrict__ rowptr, const int* __restrict__ csrc,
                const float* __restrict__ dinv, const float* __restrict__ bias,
                int n) {
    int lane = threadIdx.x & 63;
    int half = lane >> 5;          // which node of the pair
    int hl   = lane & 31;
    int grp  = hl >> 3;            // 0..3
    int sub  = lane & 7;           // 16B chunk within row
    int fl   = sub * 8;            // first feature of this lane
    const int4* H4 = (const int4*)H;   // 8 halves per int4
    int wave = (blockIdx.x * blockDim.x + threadIdx.x) >> 6;
    int nw   = (gridDim.x * blockDim.x) >> 6;
    int np   = (n + 1) >> 1;       // node pairs
    float4 bv0 = *(const float4*)(bias + fl);
    float4 bv1 = *(const float4*)(bias + fl + 4);
    int wp = wave;
    if (wp >= np) return;
    int node = min(2 * wp + half, n - 1);
    int k0 = rowptr[node], k1 = rowptr[node + 1];
    while (true) {
        // prefetch next pair's rowptr (independent of everything below)
        int wpn = wp + nw;
        int noden = 0, k0n = 0, k1n = 0;
        bool more = wpn < np;
        if (more) {
            noden = min(2 * wpn + half, n - 1);
            k0n = rowptr[noden];
            k1n = rowptr[noden + 1];
        }
        float accf[8] = {0.f, 0.f, 0.f, 0.f, 0.f, 0.f, 0.f, 0.f};
        if (grp == 0) {  // self-loop row (exec-masked: only 8 lanes/half issue)
            int4 hv = H4[(size_t)node * 8 + sub];
            const __half2* hh = (const __half2*)&hv;
#pragma unroll
            for (int j = 0; j < 4; ++j) {
                float2 f = __half22float2(hh[j]);
                accf[2 * j]     += f.x;
                accf[2 * j + 1] += f.y;
            }
        }
        for (int basek = k0; basek < k1; basek += 16) {
            int  kk0 = basek + grp;            // unroll u: slot = basek+4u+grp
            int  kk1 = kk0 + 4, kk2 = kk0 + 8, kk3 = kk0 + 12;
            bool v0 = kk0 < k1, v1 = kk1 < k1, v2 = kk2 < k1, v3 = kk3 < k1;
            int  s0 = v0 ? csrc[kk0] : 0;      // masked -> row 0 (L1-hot)
            int  s1 = v1 ? csrc[kk1] : 0;
            int  s2 = v2 ? csrc[kk2] : 0;
            int  s3 = v3 ? csrc[kk3] : 0;
            int4 h0 = H4[(size_t)s0 * 8 + sub];  // 4 independent gathers
            int4 h1 = H4[(size_t)s1 * 8 + sub];
            int4 h2 = H4[(size_t)s2 * 8 + sub];
            int4 h3 = H4[(size_t)s3 * 8 + sub];
            pairdot(h0, h1, v0, v1, accf);
            pairdot(h2, h3, v2, v3, accf);
        }
        // reduce partials across the 4 groups of this half (stride 8, 16)
#pragma unroll
        for (int j = 0; j < 8; ++j) {
            float a = accf[j];
            a += __shfl_xor(a, 8);
            a += __shfl_xor(a, 16);
            accf[j] = a;
        }
        if (grp == 0 && 2 * wp + half < n) {
            float di = dinv[node];
            float o[8];
            o[0] = fmaxf(fmaf(accf[0], di, bv0.x), 0.f);
            o[1] = fmaxf(fmaf(accf[1], di, bv0.y), 0.f);
            o[2] = fmaxf(fmaf(accf[2], di, bv0.z), 0.f);
            o[3] = fmaxf(fmaf(accf[3], di, bv0.w), 0.f);
            o[4] = fmaxf(fmaf(accf[4], di, bv1.x), 0.f);
            o[5] = fmaxf(fmaf(accf[5], di, bv1.y), 0.f);
            o[6] = fmaxf(fmaf(accf[6], di, bv1.z), 0.f);
            o[7] = fmaxf(fmaf(accf[7], di, bv1.w), 0.f);
            if constexpr (sizeof(OT) == 2) {
                __half2 hh[4];
#pragma unroll
                for (int j = 0; j < 4; ++j)
                    hh[j] = __floats2half2_rn(o[2 * j], o[2 * j + 1]);
                *(int4*)((__half*)Y + (size_t)node * 64 + fl) =
                    *(const int4*)hh;
            } else {
                float4 o0 = make_float4(o[0], o[1], o[2], o[3]);
                float4 o1 = make_float4(o[4], o[5], o[6], o[7]);
                *(float4*)((float*)Y + (size_t)node * 64 + fl)     = o0;
                *(float4*)((float*)Y + (size_t)node * 64 + fl + 4) = o1;
            }
        }
        if (!more) break;
        wp = wpn; node = noden; k0 = k0n; k1 = k1n;
    }
}

extern "C" void kernel_launch(void* const* d_in, const int* in_sizes, int n_in,
                              void* d_out, int out_size, void* d_ws, size_t ws_size,
                              hipStream_t stream) {
    const float* x  = (const float*)d_in[0];
    const int*   ei = (const int*)d_in[1];
    const float* W0 = (const float*)d_in[2];
    const float* b0 = (const float*)d_in[3];
    const float* W1 = (const float*)d_in[4];
    const float* b1 = (const float*)d_in[5];
    const float* W2 = (const float*)d_in[6];
    const float* b2 = (const float*)d_in[7];

    const int N = in_sizes[0] / 64;
    const int E = in_sizes[1] / 2;
    const int* src = ei;       // edge_index[0]
    const int* dst = ei + E;   // edge_index[1]
    const int NB = (N + BNODES - 1) >> BSH;   // 196 for N=100k (<=256)

    // ---- workspace layout (256B-aligned slices) ----
    char*  ws  = (char*)d_ws;
    size_t off = 0;
    auto alloc = [&](size_t bytes) -> void* {
        void* p = ws + off;
        off += (bytes + 255) & ~(size_t)255;
        return p;
    };
    int*    rowptr = (int*)   alloc((size_t)(N + 1) * 4);
    float*  dinv   = (float*) alloc((size_t)N * 4);
    int*    csrc   = (int*)   alloc((size_t)E * 4);
    int*    bcur   = (int*)   alloc((size_t)NB * BPAD * 4);
    int*    bbase  = (int*)   alloc((size_t)NB * 4);
    int*    sbuf   = (int*)   alloc((size_t)NB * BCAP * 4);
    __half* hbuf   = (__half*)alloc((size_t)N * 64 * 2);
    __half* act16  = (__half*)alloc((size_t)N * 64 * 2);
    float*  outb   = (float*)d_out;

    const int ngrid = 2048;   // agg (2 nodes/wave)
    const int ggrid = 1024;   // gemm (MFMA, ~6250 tiles)
    const int bgrid = (E + CHUNK - 1) / CHUNK;
    const int zn    = NB * BPAD;

    zero_kernel    <<<(zn + THREADS - 1) / THREADS, THREADS, 0, stream>>>(bcur, zn);
    bin_kernel     <<<bgrid, THREADS, 0, stream>>>(src, dst, bcur, sbuf, E);
    bscan_kernel   <<<1,     THREADS, 0, stream>>>(bcur, bbase, NB, rowptr, N, E);
    finalize_kernel<<<NB,    THREADS, 0, stream>>>(sbuf, bcur, bbase, rowptr,
                                                   dinv, csrc, N);

    // layer 0: x(f32) -> hbuf -> act16 (fp16)
    gemm64_kernel<float> <<<ggrid, THREADS, 0, stream>>>(x, hbuf, W0, dinv, N);
    agg_kernel<__half>   <<<ngrid, THREADS, 0, stream>>>(hbuf, act16, rowptr, csrc, dinv, b0, N);
    // layer 1: act16 -> hbuf -> act16
    gemm64_kernel<__half><<<ggrid, THREADS, 0, stream>>>(act16, hbuf, W1, dinv, N);
    agg_kernel<__half>   <<<ngrid, THREADS, 0, stream>>>(hbuf, act16, rowptr, csrc, dinv, b1, N);
    // layer 2: act16 -> hbuf -> d_out (fp32)
    gemm64_kernel<__half><<<ggrid, THREADS, 0, stream>>>(act16, hbuf, W2, dinv, N);
    agg_kernel<float>    <<<ngrid, THREADS, 0, stream>>>(hbuf, outb, rowptr, csrc, dinv, b2, N);
}